// Round 9
// baseline (60871.088 us; speedup 1.0000x reference)
//
#include <hip/hip_runtime.h>
#include <stdint.h>

#define N_NODES 20000
#define E_EDGES 640000
#define F1 256
#define HDIM 256
#define G3 768
#define HEADS 8
#define HC 128
#define DH 16
#define NA 8
#define MS 64

typedef _Float16 h2 __attribute__((ext_vector_type(2)));

__device__ __forceinline__ float fexp2(float x) { return __builtin_amdgcn_exp2f(x); }
__device__ __forceinline__ float frcp(float x)  { return __builtin_amdgcn_rcpf(x); }
__device__ __forceinline__ float sigm(float x)  { return frcp(1.f + fexp2(-1.44269504f * x)); }
__device__ __forceinline__ float tanh_(float x) {
  x = fminf(20.f, fmaxf(-20.f, x));
  float t = fexp2(2.88539008f * x);
  return (t - 1.f) * frcp(t + 1.f);
}
__device__ __forceinline__ float leaky(float x) { return (x > 0.f) ? x : 0.2f * x; }
__device__ __forceinline__ unsigned fenc(float f) {
  unsigned u = __float_as_uint(f);
  return (u & 0x80000000u) ? ~u : (u | 0x80000000u);
}
__device__ __forceinline__ float fdec(unsigned u) {
  return __uint_as_float((u & 0x80000000u) ? (u ^ 0x80000000u) : ~u);
}

// ---------------------------------------------------------------- generic GEMM
#define GF_BIAS 1
#define GF_RELU_OUT 2
#define GF_ACC 4
#define GF_RELU_A 8
#define GF_BT 16

template <int FLAGS>
__global__ __launch_bounds__(256) void gemm_k(const float* __restrict__ A,
                                              const float* __restrict__ B,
                                              const float* __restrict__ bias,
                                              float* __restrict__ C,
                                              int M, int K, int P) {
  __shared__ float As[64][68];
  __shared__ float Bs[64][68];
  int colTiles = P >> 6;
  int bx = blockIdx.x % colTiles;
  int by = blockIdx.x / colTiles;
  int row0 = by * 64, col0 = bx * 64;
  int tid = threadIdx.x;
  int tx = tid & 15, ty = tid >> 4;
  float acc[4][4] = {};
  for (int k0 = 0; k0 < K; k0 += 64) {
    {
      int r = tid >> 2, kq = (tid & 3) * 16;
      int gr = row0 + r;
      const float* ap = A + (size_t)gr * K + k0 + kq;
#pragma unroll
      for (int j = 0; j < 4; j++) {
        float4 v = make_float4(0.f, 0.f, 0.f, 0.f);
        if (gr < M) v = *(const float4*)(ap + 4 * j);
        if (FLAGS & GF_RELU_A) {
          v.x = fmaxf(v.x, 0.f); v.y = fmaxf(v.y, 0.f);
          v.z = fmaxf(v.z, 0.f); v.w = fmaxf(v.w, 0.f);
        }
        As[kq + 4 * j + 0][r] = v.x; As[kq + 4 * j + 1][r] = v.y;
        As[kq + 4 * j + 2][r] = v.z; As[kq + 4 * j + 3][r] = v.w;
      }
    }
    if (FLAGS & GF_BT) {
      int n = tid >> 2, kq = (tid & 3) * 16;
      const float* bp = B + (size_t)(col0 + n) * K + k0 + kq;
#pragma unroll
      for (int j = 0; j < 4; j++) {
        float4 v = *(const float4*)(bp + 4 * j);
        Bs[kq + 4 * j + 0][n] = v.x; Bs[kq + 4 * j + 1][n] = v.y;
        Bs[kq + 4 * j + 2][n] = v.z; Bs[kq + 4 * j + 3][n] = v.w;
      }
    } else {
      int kk = tid >> 2, nq = (tid & 3) * 16;
      const float* bp = B + (size_t)(k0 + kk) * P + col0 + nq;
#pragma unroll
      for (int j = 0; j < 4; j++)
        *(float4*)&Bs[kk][nq + 4 * j] = *(const float4*)(bp + 4 * j);
    }
    __syncthreads();
#pragma unroll
    for (int kk = 0; kk < 64; kk++) {
      float4 av = *(const float4*)&As[kk][ty * 4];
      float4 bv = *(const float4*)&Bs[kk][tx * 4];
      float a4[4] = {av.x, av.y, av.z, av.w};
      float b4[4] = {bv.x, bv.y, bv.z, bv.w};
#pragma unroll
      for (int i = 0; i < 4; i++)
#pragma unroll
        for (int j = 0; j < 4; j++) acc[i][j] = fmaf(a4[i], b4[j], acc[i][j]);
    }
    __syncthreads();
  }
#pragma unroll
  for (int i = 0; i < 4; i++) {
    int gr = row0 + ty * 4 + i;
    if (gr >= M) continue;
#pragma unroll
    for (int j = 0; j < 4; j++) {
      int gc = col0 + tx * 4 + j;
      float v = acc[i][j];
      if (FLAGS & GF_BIAS) v += bias[gc];
      if (FLAGS & GF_RELU_OUT) v = fmaxf(v, 0.f);
      size_t o = (size_t)gr * P + gc;
      if (FLAGS & GF_ACC) C[o] += v; else C[o] = v;
    }
  }
}

// ------------------------------------------------- GRU weight repack (fp32 -> f16 pairs)
// 512-thread scan layout (R2-verified): thread t (g=t>>2, c=t&3) owns rows
// {2g,2g+1} of each gate block, k in [64c,64c+64). uint4 slot i (0..47), comp m:
// q=4i+m, a=q>>5 (a%3=gate, a/3=row half), p=q&31: row=(a%3)*256+2g+(a/3), k=64c+2p.
// Buffer: uint4 index i*512+t.
__global__ __launch_bounds__(256) void prep_w(const float* __restrict__ Whh,
                                              uint32_t* __restrict__ Wpk) {
  int idx = blockIdx.x * 256 + threadIdx.x;  // dword index
  if (idx >= 48 * 2048) return;
  int i = idx >> 11;
  int rem = idx & 2047;
  int t = rem >> 2, comp = rem & 3;
  int q = 4 * i + comp;
  int g = t >> 2, c = t & 3;
  int a = q >> 5, p = q & 31;
  int row = (a % 3) * 256 + 2 * g + (a / 3);
  int k = 64 * c + 2 * p;
  h2 v = { (_Float16)Whh[row * 256 + k], (_Float16)Whh[row * 256 + k + 1] };
  Wpk[idx] = __builtin_bit_cast(uint32_t, v);
}

// combined bias for the GI GEMM: bih + bhh for r,z rows (folded), bih only for n rows
__global__ __launch_bounds__(256) void prep_b(const float* __restrict__ bih,
                                              const float* __restrict__ bhh,
                                              float* __restrict__ b2) {
  int i = blockIdx.x * 256 + threadIdx.x;
  if (i < G3) b2[i] = bih[i] + (i < 512 ? bhh[i] : 0.f);
}

// ---------------------------------------------------------------- GRU scan v4: hard-reg asm islands
// R3/R6/R7 lesson: no attribute makes the allocator hold 96+ loop-invariant regs;
// it spills to L2 scratch (measured 3072 cyc/step = L2 stream floor). So we take
// the registers away from it: weights live in PHYSICAL v[64:255], written once by
// v_mov asm (clobbers declared). Clobbered regs count toward VGPR_Count -> 256
// -> exactly 8 waves/CU = one 512-thread block. Dots are asm with tied "+v"
// accumulators and LDS-read h as "v" inputs (compiler still handles waitcnt).
// (R8 failure was mechanical: WLOAD's do/while needs terminating semicolons.)
#define WLOAD(i, R0, R1, R2, R3) do { uint4 w_ = Wp4[(i) * 512 + tid]; \
  asm volatile("v_mov_b32 " R0 ", %0\n\tv_mov_b32 " R1 ", %1\n\tv_mov_b32 " R2 \
               ", %2\n\tv_mov_b32 " R3 ", %3" \
               :: "v"(w_.x), "v"(w_.y), "v"(w_.z), "v"(w_.w) : R0, R1, R2, R3); } while (0)

#define DOTM(HX, A0, A1, A2, A3, A4, A5) \
  asm volatile("v_dot2_f32_f16 %0, " A0 ", %6, %0\n\t" \
               "v_dot2_f32_f16 %1, " A1 ", %6, %1\n\t" \
               "v_dot2_f32_f16 %2, " A2 ", %6, %2\n\t" \
               "v_dot2_f32_f16 %3, " A3 ", %6, %3\n\t" \
               "v_dot2_f32_f16 %4, " A4 ", %6, %4\n\t" \
               "v_dot2_f32_f16 %5, " A5 ", %6, %5" \
               : "+v"(a0), "+v"(a1), "+v"(a2), "+v"(a3), "+v"(a4), "+v"(a5) \
               : "v"(HX));

__global__ __launch_bounds__(512) void gru_scan(const float* __restrict__ GI,
                                                const uint32_t* __restrict__ Wpk,
                                                const float* __restrict__ bhh,
                                                float* __restrict__ Hout) {
  __shared__ __align__(16) uint32_t hb[2][4][36];
  int tid = threadIdx.x;
  int g = tid >> 2, c = tid & 3;
  int lane = tid & 63;
  const uint4* Wp4 = (const uint4*)Wpk;
  // ---- load weights into hard regs v[64:255] (48 uint4)
  WLOAD(0,"v64","v65","v66","v67");     WLOAD(1,"v68","v69","v70","v71");
  WLOAD(2,"v72","v73","v74","v75");     WLOAD(3,"v76","v77","v78","v79");
  WLOAD(4,"v80","v81","v82","v83");     WLOAD(5,"v84","v85","v86","v87");
  WLOAD(6,"v88","v89","v90","v91");     WLOAD(7,"v92","v93","v94","v95");
  WLOAD(8,"v96","v97","v98","v99");     WLOAD(9,"v100","v101","v102","v103");
  WLOAD(10,"v104","v105","v106","v107"); WLOAD(11,"v108","v109","v110","v111");
  WLOAD(12,"v112","v113","v114","v115"); WLOAD(13,"v116","v117","v118","v119");
  WLOAD(14,"v120","v121","v122","v123"); WLOAD(15,"v124","v125","v126","v127");
  WLOAD(16,"v128","v129","v130","v131"); WLOAD(17,"v132","v133","v134","v135");
  WLOAD(18,"v136","v137","v138","v139"); WLOAD(19,"v140","v141","v142","v143");
  WLOAD(20,"v144","v145","v146","v147"); WLOAD(21,"v148","v149","v150","v151");
  WLOAD(22,"v152","v153","v154","v155"); WLOAD(23,"v156","v157","v158","v159");
  WLOAD(24,"v160","v161","v162","v163"); WLOAD(25,"v164","v165","v166","v167");
  WLOAD(26,"v168","v169","v170","v171"); WLOAD(27,"v172","v173","v174","v175");
  WLOAD(28,"v176","v177","v178","v179"); WLOAD(29,"v180","v181","v182","v183");
  WLOAD(30,"v184","v185","v186","v187"); WLOAD(31,"v188","v189","v190","v191");
  WLOAD(32,"v192","v193","v194","v195"); WLOAD(33,"v196","v197","v198","v199");
  WLOAD(34,"v200","v201","v202","v203"); WLOAD(35,"v204","v205","v206","v207");
  WLOAD(36,"v208","v209","v210","v211"); WLOAD(37,"v212","v213","v214","v215");
  WLOAD(38,"v216","v217","v218","v219"); WLOAD(39,"v220","v221","v222","v223");
  WLOAD(40,"v224","v225","v226","v227"); WLOAD(41,"v228","v229","v230","v231");
  WLOAD(42,"v232","v233","v234","v235"); WLOAD(43,"v236","v237","v238","v239");
  WLOAD(44,"v240","v241","v242","v243"); WLOAD(45,"v244","v245","v246","v247");
  WLOAD(46,"v248","v249","v250","v251"); WLOAD(47,"v252","v253","v254","v255");
  for (int i = tid; i < 2 * 4 * 36; i += 512) ((uint32_t*)hb)[i] = 0;
  bool wr = (blockIdx.x == 0);
  bool gatel = ((c & 1) == 0);
  int j = 2 * g + (c >> 1);
  float bh_n = 0.f, hreg = 0.f;
  if (gatel) bh_n = bhh[512 + j];
  __syncthreads();
  int buf = 0;
  const int bl = lane & ~3;
#pragma unroll 1
  for (int t = 0; t < N_NODES; t++) {
    float gr = 0.f, gz = 0.f, gn = 0.f;
    if (gatel) {
      const float* gp = GI + (size_t)t * G3;
      gr = gp[j]; gz = gp[256 + j]; gn = gp[512 + j];
    }
    float a0 = 0.f, a1 = 0.f, a2 = 0.f, a3 = 0.f, a4 = 0.f, a5 = 0.f;
    const uint4* hc4 = (const uint4*)(&hb[buf][c][0]);
    uint4 Ha = hc4[0], Hb = hc4[1];
    // batch b uses weight regs v[64+32a+4b+m] for gate a, comp m
    DOTM(Ha.x,"v64","v96","v128","v160","v192","v224")
    DOTM(Ha.y,"v65","v97","v129","v161","v193","v225")
    DOTM(Ha.z,"v66","v98","v130","v162","v194","v226")
    DOTM(Ha.w,"v67","v99","v131","v163","v195","v227")
    Ha = hc4[2];
    DOTM(Hb.x,"v68","v100","v132","v164","v196","v228")
    DOTM(Hb.y,"v69","v101","v133","v165","v197","v229")
    DOTM(Hb.z,"v70","v102","v134","v166","v198","v230")
    DOTM(Hb.w,"v71","v103","v135","v167","v199","v231")
    Hb = hc4[3];
    DOTM(Ha.x,"v72","v104","v136","v168","v200","v232")
    DOTM(Ha.y,"v73","v105","v137","v169","v201","v233")
    DOTM(Ha.z,"v74","v106","v138","v170","v202","v234")
    DOTM(Ha.w,"v75","v107","v139","v171","v203","v235")
    Ha = hc4[4];
    DOTM(Hb.x,"v76","v108","v140","v172","v204","v236")
    DOTM(Hb.y,"v77","v109","v141","v173","v205","v237")
    DOTM(Hb.z,"v78","v110","v142","v174","v206","v238")
    DOTM(Hb.w,"v79","v111","v143","v175","v207","v239")
    Hb = hc4[5];
    DOTM(Ha.x,"v80","v112","v144","v176","v208","v240")
    DOTM(Ha.y,"v81","v113","v145","v177","v209","v241")
    DOTM(Ha.z,"v82","v114","v146","v178","v210","v242")
    DOTM(Ha.w,"v83","v115","v147","v179","v211","v243")
    Ha = hc4[6];
    DOTM(Hb.x,"v84","v116","v148","v180","v212","v244")
    DOTM(Hb.y,"v85","v117","v149","v181","v213","v245")
    DOTM(Hb.z,"v86","v118","v150","v182","v214","v246")
    DOTM(Hb.w,"v87","v119","v151","v183","v215","v247")
    Hb = hc4[7];
    DOTM(Ha.x,"v88","v120","v152","v184","v216","v248")
    DOTM(Ha.y,"v89","v121","v153","v185","v217","v249")
    DOTM(Ha.z,"v90","v122","v154","v186","v218","v250")
    DOTM(Ha.w,"v91","v123","v155","v187","v219","v251")
    DOTM(Hb.x,"v92","v124","v156","v188","v220","v252")
    DOTM(Hb.y,"v93","v125","v157","v189","v221","v253")
    DOTM(Hb.z,"v94","v126","v158","v190","v222","v254")
    DOTM(Hb.w,"v95","v127","v159","v191","v223","v255")
    // butterfly over the 4 chunk lanes: slots [r0,z0,n0,r1,z1,n1,0,0] (R2-verified)
    float v6 = 0.f, v7 = 0.f;
    float u0, u1, u2, u3;
    {
      float t0 = __shfl_xor(a0, 2, 64), t4 = __shfl_xor(a4, 2, 64);
      u0 = (c & 2) ? a4 + t4 : a0 + t0;
      float t1 = __shfl_xor(a1, 2, 64), t5 = __shfl_xor(a5, 2, 64);
      u1 = (c & 2) ? a5 + t5 : a1 + t1;
      float t2 = __shfl_xor(a2, 2, 64), t6 = __shfl_xor(v6, 2, 64);
      u2 = (c & 2) ? v6 + t6 : a2 + t2;
      float t3 = __shfl_xor(a3, 2, 64), t7 = __shfl_xor(v7, 2, 64);
      u3 = (c & 2) ? v7 + t7 : a3 + t3;
    }
    float f0, f1;
    {
      float t0 = __shfl_xor(u0, 1, 64), t2 = __shfl_xor(u2, 1, 64);
      f0 = (c & 1) ? u2 + t2 : u0 + t0;
      float t1 = __shfl_xor(u1, 1, 64), t3 = __shfl_xor(u3, 1, 64);
      f1 = (c & 1) ? u3 + t3 : u1 + t1;
    }
    float ta = __shfl(f0, bl + 1, 64);
    float tb = __shfl(f1, bl + 1, 64);
    if (gatel) {
      float Sr = (c == 0) ? f0 : tb;
      float Sz = (c == 0) ? f1 : f0;
      float Sn = (c == 0) ? ta : f1;
      float r = sigm(gr + Sr);             // bhh_r/z folded into GI bias
      float z = sigm(gz + Sz);
      float n = tanh_(gn + r * (Sn + bh_n));
      float hn = (1.f - z) * n + z * hreg;
      hreg = hn;
      if (wr) Hout[(size_t)t * HDIM + j] = hn;
      int pj = j >> 1, cc = pj >> 5, half = j & 1;
      ushort* hw = (ushort*)&hb[buf ^ 1][cc][0];
      hw[(pj & 31) * 2 + half] = __builtin_bit_cast(uint16_t, (_Float16)hn);
    }
    __syncthreads();
    buf ^= 1;
  }
}

// ---------------------------------------------------------------- GAT pieces
__global__ __launch_bounds__(256) void esed_k(const float* __restrict__ Hg,
                                              const float* __restrict__ a_s,
                                              const float* __restrict__ a_d,
                                              float* __restrict__ es, float* __restrict__ ed) {
  int idx = blockIdx.x * 256 + threadIdx.x;
  if (idx >= N_NODES * HEADS) return;
  int n = idx >> 3, hd = idx & 7;
  const float* hp = Hg + (size_t)n * HC + hd * DH;
  float s = 0, d = 0;
#pragma unroll
  for (int i = 0; i < DH; i++) {
    float h = hp[i];
    s = fmaf(h, a_s[hd * DH + i], s);
    d = fmaf(h, a_d[hd * DH + i], d);
  }
  es[idx] = s; ed[idx] = d;
}

__global__ __launch_bounds__(256) void esmax_k(const float* __restrict__ es,
                                               unsigned* __restrict__ m) {
  int idx = blockIdx.x * 256 + threadIdx.x;
  float v = (idx < N_NODES * HEADS) ? es[idx] : -1e30f;
#pragma unroll
  for (int mask = 32; mask >= 8; mask >>= 1) v = fmaxf(v, __shfl_xor(v, mask, 64));
  if ((threadIdx.x & 63) < 8) atomicMax(&m[threadIdx.x & 7], fenc(v));
}

// ---------------------------------------------------------------- CSR build
__global__ __launch_bounds__(256) void deg_k(const int* __restrict__ ei, int* __restrict__ deg) {
  int e = blockIdx.x * 256 + threadIdx.x;
  if (e >= E_EDGES) return;
  atomicAdd(&deg[ei[E_EDGES + e]], 1);
}

__global__ __launch_bounds__(1024) void scan_k(const int* __restrict__ deg, int* __restrict__ off) {
  __shared__ int wsum[16];
  __shared__ int carry;
  int tid = threadIdx.x, lane = tid & 63, wv = tid >> 6;
  if (tid == 0) carry = 0;
  __syncthreads();
  for (int base = 0; base < N_NODES; base += 1024) {
    int i = base + tid;
    int v = (i < N_NODES) ? deg[i] : 0;
    int s = v;
#pragma unroll
    for (int d = 1; d < 64; d <<= 1) {
      int t = __shfl_up(s, d, 64);
      if (lane >= d) s += t;
    }
    if (lane == 63) wsum[wv] = s;
    __syncthreads();
    if (wv == 0 && lane < 16) {
      int t = wsum[lane];
#pragma unroll
      for (int d = 1; d < 16; d <<= 1) {
        int u = __shfl_up(t, d, 64);
        if (lane >= d) t += u;
      }
      wsum[lane] = t;
    }
    __syncthreads();
    int prev = (wv > 0) ? wsum[wv - 1] : 0;
    int excl = carry + prev + s - v;
    if (i < N_NODES) off[i] = excl;
    int total = wsum[15];
    __syncthreads();
    if (tid == 0) carry += total;
    __syncthreads();
  }
  if (tid == 0) off[N_NODES] = carry;
}

__global__ __launch_bounds__(256) void scatter_k(const int* __restrict__ ei,
                                                 const int* __restrict__ off,
                                                 int* __restrict__ cnt,
                                                 int* __restrict__ csr_src) {
  int e = blockIdx.x * 256 + threadIdx.x;
  if (e >= E_EDGES) return;
  int d = ei[E_EDGES + e];
  int pos = off[d] + atomicAdd(&cnt[d], 1);
  csr_src[pos] = ei[e];
}

// ---------------------------------------------------------------- GAT gather (1 wave / dst)
template <int RELU>
__global__ __launch_bounds__(256) void gather_k(const int* __restrict__ off,
                                                const int* __restrict__ csr_src,
                                                const float* __restrict__ es,
                                                const float* __restrict__ ed,
                                                const unsigned* __restrict__ esm,
                                                const float* __restrict__ Hg,
                                                const float* __restrict__ bias,
                                                float* __restrict__ out) {
  int wv = threadIdx.x >> 6, lane = threadIdx.x & 63;
  int d = blockIdx.x * 4 + wv;
  if (d >= N_NODES) return;
  int hd0 = lane >> 4, hd1 = 4 + (lane >> 4);
  float ed0 = ed[d * 8 + hd0], ed1 = ed[d * 8 + hd1];
  float cb0 = leaky(fdec(esm[hd0]) + ed0);
  float cb1 = leaky(fdec(esm[hd1]) + ed1);
  int e0 = off[d], e1 = off[d + 1];
  float acc0 = 0, acc1 = 0, den0 = 0, den1 = 0;
  for (int i = e0; i < e1; i++) {
    int s = csr_src[i];
    float p0 = fexp2(1.44269504f * (leaky(es[s * 8 + hd0] + ed0) - cb0));
    float p1 = fexp2(1.44269504f * (leaky(es[s * 8 + hd1] + ed1) - cb1));
    float h0 = Hg[(size_t)s * HC + lane];
    float h1 = Hg[(size_t)s * HC + 64 + lane];
    acc0 = fmaf(p0, h0, acc0); acc1 = fmaf(p1, h1, acc1);
    den0 += p0; den1 += p1;
  }
  float o0 = acc0 * frcp(den0 + 1e-16f);
  float o1 = acc1 * frcp(den1 + 1e-16f);
  if (RELU) {
    o0 = fmaxf(o0 + bias[lane], 0.f);
    o1 = fmaxf(o1 + bias[64 + lane], 0.f);
  }
  out[(size_t)d * HC + lane] = o0;
  out[(size_t)d * HC + 64 + lane] = o1;
}

// ---------------------------------------------------------------- output heads
__global__ __launch_bounds__(64) void heads_k(const float* __restrict__ xgb,
                                              const float* __restrict__ bg2,
                                              const float* __restrict__ H2,
                                              const float* __restrict__ Wc, const float* __restrict__ bc,
                                              const float* __restrict__ Wmu, const float* __restrict__ bmu,
                                              const float* __restrict__ Wm, const float* __restrict__ bm,
                                              float* __restrict__ out) {
  int n = blockIdx.x, l = threadIdx.x;
  __shared__ float xg[HC];
  __shared__ float xr[HDIM];
  for (int i = l; i < HC; i += 64) xg[i] = xgb[(size_t)n * HC + i] + bg2[i];
  for (int i = l; i < HDIM; i += 64) xr[i] = fmaxf(H2[(size_t)n * HDIM + i], 0.f);
  __syncthreads();
  float acc = bm[l];
#pragma unroll 8
  for (int k = 0; k < HC; k++) acc = fmaf(xg[k], Wm[k * MS + l], acc);
  out[N_NODES + (size_t)n * MS + l] = tanh_(acc);
  if (l < NA) {
    float a = bmu[l];
    for (int k = 0; k < HDIM; k++) a = fmaf(xr[k], Wmu[k * NA + l], a);
    for (int k = 0; k < HC; k++) a = fmaf(xg[k], Wmu[(HDIM + k) * NA + l], a);
    out[N_NODES + (size_t)N_NODES * MS + (size_t)n * NA + l] = tanh_(a);
  }
  if (l == 0) {
    float a = bc[0];
    for (int k = 0; k < HC; k++) a = fmaf(xg[k], Wc[k], a);
    out[n] = sigm(a);
  }
}

// ---------------------------------------------------------------- launch
extern "C" void kernel_launch(void* const* d_in, const int* in_sizes, int n_in,
                              void* d_out, int out_size, void* d_ws, size_t ws_size,
                              hipStream_t stream) {
  const float* state = (const float*)d_in[0];
  const float* message = (const float*)d_in[1];
  const int* ei = (const int*)d_in[2];
  const float* Wfc1 = (const float*)d_in[3]; const float* bfc1 = (const float*)d_in[4];
  const float* Wfc2 = (const float*)d_in[5]; const float* bfc2 = (const float*)d_in[6];
  const float* Wih0 = (const float*)d_in[7]; const float* Whh0 = (const float*)d_in[8];
  const float* bih0 = (const float*)d_in[9]; const float* bhh0 = (const float*)d_in[10];
  const float* Wih1 = (const float*)d_in[11]; const float* Whh1 = (const float*)d_in[12];
  const float* bih1 = (const float*)d_in[13]; const float* bhh1 = (const float*)d_in[14];
  const float* Wg1 = (const float*)d_in[15]; const float* as1 = (const float*)d_in[16];
  const float* ad1 = (const float*)d_in[17]; const float* bg1 = (const float*)d_in[18];
  const float* Wg2 = (const float*)d_in[19]; const float* as2 = (const float*)d_in[20];
  const float* ad2 = (const float*)d_in[21]; const float* bg2 = (const float*)d_in[22];
  const float* Wc = (const float*)d_in[23]; const float* bc = (const float*)d_in[24];
  const float* Wmu = (const float*)d_in[25]; const float* bmu = (const float*)d_in[26];
  const float* Wm = (const float*)d_in[27]; const float* bm = (const float*)d_in[28];

  float* ws = (float*)d_ws;
  float* GI = ws;                       // [20000 x 768]; dead after scans, region reused:
  float* HGa = ws;                      //   [20000 x 128] gat h
  float* HGb = ws + 2560000;            //   [20000 x 128] aggregation out (layer2)
  float* X2  = ws + 5120000;            //   [20000 x 128] relu(gat1+bg1)
  float* ES  = ws + 7680000;            //   [20000 x 8]
  float* ED  = ws + 7840000;            //   [20000 x 8]
  unsigned* ESM = (unsigned*)(ws + 8160000);  // [8]
  int* DEG = (int*)(ws + 8200000);      //   [20000]
  int* OFF = (int*)(ws + 8230000);      //   [20001]
  int* CNT = (int*)(ws + 8260000);      //   [20000]
  int* CSR = (int*)(ws + 8300000);      //   [640000]
  float* X  = ws + 15360000;            // [20000 x 256], reused as H1
  float* H2 = ws + 20480000;            // [20000 x 256]
  // B2 in the H2 region head: dead during both GI GEMMs, overwritten by scan 1.
  float* B2  = H2;                      //   [768] combined GI bias
  uint32_t* Wpk = (uint32_t*)(ws + 25600000); // [48*512 uint4]
  float* out = (float*)d_out;

  int rt = (N_NODES + 63) / 64;  // 313 row tiles

  gemm_k<GF_BIAS | GF_RELU_OUT><<<rt * 4, 256, 0, stream>>>(state, Wfc1, bfc1, X, N_NODES, 64, 256);
  gemm_k<GF_BIAS | GF_RELU_OUT | GF_ACC><<<rt * 4, 256, 0, stream>>>(message, Wfc2, bfc2, X, N_NODES, 64, 256);
  // GRU layer 0
  prep_b<<<3, 256, 0, stream>>>(bih0, bhh0, B2);
  gemm_k<GF_BIAS | GF_BT><<<rt * 12, 256, 0, stream>>>(X, Wih0, B2, GI, N_NODES, 256, G3);
  prep_w<<<384, 256, 0, stream>>>(Whh0, Wpk);
  gru_scan<<<64, 512, 0, stream>>>(GI, Wpk, bhh0, X);  // H1 overwrites X
  // GRU layer 1
  prep_b<<<3, 256, 0, stream>>>(bih1, bhh1, B2);
  gemm_k<GF_BIAS | GF_BT><<<rt * 12, 256, 0, stream>>>(X, Wih1, B2, GI, N_NODES, 256, G3);
  prep_w<<<384, 256, 0, stream>>>(Whh1, Wpk);
  gru_scan<<<64, 512, 0, stream>>>(GI, Wpk, bhh1, H2);
  // CSR build
  hipMemsetAsync(DEG, 0, N_NODES * 4, stream);
  hipMemsetAsync(CNT, 0, N_NODES * 4, stream);
  deg_k<<<2500, 256, 0, stream>>>(ei, DEG);
  scan_k<<<1, 1024, 0, stream>>>(DEG, OFF);
  scatter_k<<<2500, 256, 0, stream>>>(ei, OFF, CNT, CSR);
  // GAT layer 1
  gemm_k<GF_RELU_A><<<rt * 2, 256, 0, stream>>>(H2, Wg1, nullptr, HGa, N_NODES, 256, HC);
  esed_k<<<625, 256, 0, stream>>>(HGa, as1, ad1, ES, ED);
  hipMemsetAsync(ESM, 0, 8 * 4, stream);
  esmax_k<<<625, 256, 0, stream>>>(ES, ESM);
  gather_k<1><<<5000, 256, 0, stream>>>(OFF, CSR, ES, ED, ESM, HGa, bg1, X2);
  // GAT layer 2
  gemm_k<0><<<rt * 2, 256, 0, stream>>>(X2, Wg2, nullptr, HGa, N_NODES, HC, HC);
  esed_k<<<625, 256, 0, stream>>>(HGa, as2, ad2, ES, ED);
  hipMemsetAsync(ESM, 0, 8 * 4, stream);
  esmax_k<<<625, 256, 0, stream>>>(ES, ESM);
  gather_k<0><<<5000, 256, 0, stream>>>(OFF, CSR, ES, ED, ESM, HGa, nullptr, HGb);
  // heads
  heads_k<<<N_NODES, 64, 0, stream>>>(HGb, bg2, H2, Wc, bc, Wmu, bmu, Wm, bm, out);
}

// Round 10
// 52549.750 us; speedup vs baseline: 1.1584x; 1.1584x over previous
//
#include <hip/hip_runtime.h>
#include <stdint.h>

#define N_NODES 20000
#define E_EDGES 640000
#define F1 256
#define HDIM 256
#define G3 768
#define HEADS 8
#define HC 128
#define DH 16
#define NA 8
#define MS 64

typedef _Float16 h2 __attribute__((ext_vector_type(2)));

__device__ __forceinline__ float fexp2(float x) { return __builtin_amdgcn_exp2f(x); }
__device__ __forceinline__ float frcp(float x)  { return __builtin_amdgcn_rcpf(x); }
__device__ __forceinline__ float sigm(float x)  { return frcp(1.f + fexp2(-1.44269504f * x)); }
__device__ __forceinline__ float tanh_(float x) {
  x = fminf(20.f, fmaxf(-20.f, x));
  float t = fexp2(2.88539008f * x);
  return (t - 1.f) * frcp(t + 1.f);
}
__device__ __forceinline__ float leaky(float x) { return (x > 0.f) ? x : 0.2f * x; }
__device__ __forceinline__ unsigned fenc(float f) {
  unsigned u = __float_as_uint(f);
  return (u & 0x80000000u) ? ~u : (u | 0x80000000u);
}
__device__ __forceinline__ float fdec(unsigned u) {
  return __uint_as_float((u & 0x80000000u) ? (u ^ 0x80000000u) : ~u);
}

// ---------------------------------------------------------------- generic GEMM
#define GF_BIAS 1
#define GF_RELU_OUT 2
#define GF_ACC 4
#define GF_RELU_A 8
#define GF_BT 16

template <int FLAGS>
__global__ __launch_bounds__(256) void gemm_k(const float* __restrict__ A,
                                              const float* __restrict__ B,
                                              const float* __restrict__ bias,
                                              float* __restrict__ C,
                                              int M, int K, int P) {
  __shared__ float As[64][68];
  __shared__ float Bs[64][68];
  int colTiles = P >> 6;
  int bx = blockIdx.x % colTiles;
  int by = blockIdx.x / colTiles;
  int row0 = by * 64, col0 = bx * 64;
  int tid = threadIdx.x;
  int tx = tid & 15, ty = tid >> 4;
  float acc[4][4] = {};
  for (int k0 = 0; k0 < K; k0 += 64) {
    {
      int r = tid >> 2, kq = (tid & 3) * 16;
      int gr = row0 + r;
      const float* ap = A + (size_t)gr * K + k0 + kq;
#pragma unroll
      for (int j = 0; j < 4; j++) {
        float4 v = make_float4(0.f, 0.f, 0.f, 0.f);
        if (gr < M) v = *(const float4*)(ap + 4 * j);
        if (FLAGS & GF_RELU_A) {
          v.x = fmaxf(v.x, 0.f); v.y = fmaxf(v.y, 0.f);
          v.z = fmaxf(v.z, 0.f); v.w = fmaxf(v.w, 0.f);
        }
        As[kq + 4 * j + 0][r] = v.x; As[kq + 4 * j + 1][r] = v.y;
        As[kq + 4 * j + 2][r] = v.z; As[kq + 4 * j + 3][r] = v.w;
      }
    }
    if (FLAGS & GF_BT) {
      int n = tid >> 2, kq = (tid & 3) * 16;
      const float* bp = B + (size_t)(col0 + n) * K + k0 + kq;
#pragma unroll
      for (int j = 0; j < 4; j++) {
        float4 v = *(const float4*)(bp + 4 * j);
        Bs[kq + 4 * j + 0][n] = v.x; Bs[kq + 4 * j + 1][n] = v.y;
        Bs[kq + 4 * j + 2][n] = v.z; Bs[kq + 4 * j + 3][n] = v.w;
      }
    } else {
      int kk = tid >> 2, nq = (tid & 3) * 16;
      const float* bp = B + (size_t)(k0 + kk) * P + col0 + nq;
#pragma unroll
      for (int j = 0; j < 4; j++)
        *(float4*)&Bs[kk][nq + 4 * j] = *(const float4*)(bp + 4 * j);
    }
    __syncthreads();
#pragma unroll
    for (int kk = 0; kk < 64; kk++) {
      float4 av = *(const float4*)&As[kk][ty * 4];
      float4 bv = *(const float4*)&Bs[kk][tx * 4];
      float a4[4] = {av.x, av.y, av.z, av.w};
      float b4[4] = {bv.x, bv.y, bv.z, bv.w};
#pragma unroll
      for (int i = 0; i < 4; i++)
#pragma unroll
        for (int j = 0; j < 4; j++) acc[i][j] = fmaf(a4[i], b4[j], acc[i][j]);
    }
    __syncthreads();
  }
#pragma unroll
  for (int i = 0; i < 4; i++) {
    int gr = row0 + ty * 4 + i;
    if (gr >= M) continue;
#pragma unroll
    for (int j = 0; j < 4; j++) {
      int gc = col0 + tx * 4 + j;
      float v = acc[i][j];
      if (FLAGS & GF_BIAS) v += bias[gc];
      if (FLAGS & GF_RELU_OUT) v = fmaxf(v, 0.f);
      size_t o = (size_t)gr * P + gc;
      if (FLAGS & GF_ACC) C[o] += v; else C[o] = v;
    }
  }
}

// ------------------------------------------------- GRU weight repack (fp32 -> f16 pairs)
// 1024-thread scan layout (R5-verified): thread t (g=t>>2, c=t&3) owns rows
// {g,256+g,512+g}, k in [64c,64c+64). 24 uint4/thread: slot i, comp m -> q=4i+m:
// gate a=q>>5, pair p=q&31: row=a*256+g, k=64c+2p. Dword index = i*4096 + t*4 + m.
__global__ __launch_bounds__(256) void prep_w(const float* __restrict__ Whh,
                                              uint32_t* __restrict__ Wpk) {
  int idx = blockIdx.x * 256 + threadIdx.x;  // dword index
  if (idx >= 24 * 4096) return;
  int i = idx >> 12;
  int rem = idx & 4095;
  int t = rem >> 2, comp = rem & 3;
  int q = 4 * i + comp;
  int g = t >> 2, c = t & 3;
  int a = q >> 5, p = q & 31;
  int row = a * 256 + g;
  int k = 64 * c + 2 * p;
  h2 v = { (_Float16)Whh[row * 256 + k], (_Float16)Whh[row * 256 + k + 1] };
  Wpk[idx] = __builtin_bit_cast(uint32_t, v);
}

// combined bias for the GI GEMM: bih + bhh for r,z rows (folded), bih only for n rows
__global__ __launch_bounds__(256) void prep_b(const float* __restrict__ bih,
                                              const float* __restrict__ bhh,
                                              float* __restrict__ b2) {
  int i = blockIdx.x * 256 + threadIdx.x;
  if (i < G3) b2[i] = bih[i] + (i < 512 ? bhh[i] : 0.f);
}

// ---------------------------------------------------------------- GRU scan v5:
// 1024 threads (R5 structure: 4 waves/SIMD TLP, 96 dots/thread, uniform gates)
// + hard-reg weights (R9 technique: physical v32..v127, allocator can't spill).
// VGPR = 128 -> all 16 waves resident. Compiler gets v0..v31 (~30 live values).
// Floor: 768 cyc/step VALU issue; overhead now latency-hidden by 4 waves/SIMD.
#define WL(i, R0, R1, R2, R3) do { uint4 w_ = Wp4[(i) * 1024 + tid]; \
  asm volatile("v_mov_b32 " R0 ", %0\n\tv_mov_b32 " R1 ", %1\n\tv_mov_b32 " R2 \
               ", %2\n\tv_mov_b32 " R3 ", %3" \
               :: "v"(w_.x), "v"(w_.y), "v"(w_.z), "v"(w_.w) : R0, R1, R2, R3); } while (0)

#define DOT3(HX, R0, R1, R2) \
  asm volatile("v_dot2_f32_f16 %0, " R0 ", %3, %0\n\t" \
               "v_dot2_f32_f16 %1, " R1 ", %3, %1\n\t" \
               "v_dot2_f32_f16 %2, " R2 ", %3, %2" \
               : "+v"(s0), "+v"(s1), "+v"(s2) : "v"(HX));

__global__ __launch_bounds__(1024) void gru_scan(const float* __restrict__ GI,
                                                 const uint32_t* __restrict__ Wpk,
                                                 const float* __restrict__ bhh,
                                                 float* __restrict__ Hout) {
  __shared__ __align__(16) uint32_t hb[2][4][36];
  int tid = threadIdx.x;
  int g = tid >> 2, c = tid & 3;
  const uint4* Wp4 = (const uint4*)Wpk;
  // weights -> physical v[32:127]; slot i occupies v[32+4i .. 32+4i+3]
  WL(0,"v32","v33","v34","v35");    WL(1,"v36","v37","v38","v39");
  WL(2,"v40","v41","v42","v43");    WL(3,"v44","v45","v46","v47");
  WL(4,"v48","v49","v50","v51");    WL(5,"v52","v53","v54","v55");
  WL(6,"v56","v57","v58","v59");    WL(7,"v60","v61","v62","v63");
  WL(8,"v64","v65","v66","v67");    WL(9,"v68","v69","v70","v71");
  WL(10,"v72","v73","v74","v75");   WL(11,"v76","v77","v78","v79");
  WL(12,"v80","v81","v82","v83");   WL(13,"v84","v85","v86","v87");
  WL(14,"v88","v89","v90","v91");   WL(15,"v92","v93","v94","v95");
  WL(16,"v96","v97","v98","v99");   WL(17,"v100","v101","v102","v103");
  WL(18,"v104","v105","v106","v107"); WL(19,"v108","v109","v110","v111");
  WL(20,"v112","v113","v114","v115"); WL(21,"v116","v117","v118","v119");
  WL(22,"v120","v121","v122","v123"); WL(23,"v124","v125","v126","v127");
  for (int i = tid; i < 2 * 4 * 36; i += 1024) ((uint32_t*)hb)[i] = 0;
  bool wr = (blockIdx.x == 0);
  float bh_n = bhh[512 + g];
  float hreg = 0.f;
  __syncthreads();
  int buf = 0;
#pragma unroll 1
  for (int t = 0; t < N_NODES; t++) {
    const float* gp = GI + (size_t)t * G3;
    float gr = gp[g], gz = gp[256 + g], gn = gp[512 + g];
    float s0 = 0.f, s1 = 0.f, s2 = 0.f;
    const uint4* hc4 = (const uint4*)(&hb[buf][c][0]);
    uint4 Ha = hc4[0], Hb = hc4[1];
    // block b, gate a uses v[32 + 4*(a*8+b) + m]
    DOT3(Ha.x,"v32","v64","v96")   DOT3(Ha.y,"v33","v65","v97")
    DOT3(Ha.z,"v34","v66","v98")   DOT3(Ha.w,"v35","v67","v99")
    Ha = hc4[2];
    DOT3(Hb.x,"v36","v68","v100")  DOT3(Hb.y,"v37","v69","v101")
    DOT3(Hb.z,"v38","v70","v102")  DOT3(Hb.w,"v39","v71","v103")
    Hb = hc4[3];
    DOT3(Ha.x,"v40","v72","v104")  DOT3(Ha.y,"v41","v73","v105")
    DOT3(Ha.z,"v42","v74","v106")  DOT3(Ha.w,"v43","v75","v107")
    Ha = hc4[4];
    DOT3(Hb.x,"v44","v76","v108")  DOT3(Hb.y,"v45","v77","v109")
    DOT3(Hb.z,"v46","v78","v110")  DOT3(Hb.w,"v47","v79","v111")
    Hb = hc4[5];
    DOT3(Ha.x,"v48","v80","v112")  DOT3(Ha.y,"v49","v81","v113")
    DOT3(Ha.z,"v50","v82","v114")  DOT3(Ha.w,"v51","v83","v115")
    Ha = hc4[6];
    DOT3(Hb.x,"v52","v84","v116")  DOT3(Hb.y,"v53","v85","v117")
    DOT3(Hb.z,"v54","v86","v118")  DOT3(Hb.w,"v55","v87","v119")
    Hb = hc4[7];
    DOT3(Ha.x,"v56","v88","v120")  DOT3(Ha.y,"v57","v89","v121")
    DOT3(Ha.z,"v58","v90","v122")  DOT3(Ha.w,"v59","v91","v123")
    DOT3(Hb.x,"v60","v92","v124")  DOT3(Hb.y,"v61","v93","v125")
    DOT3(Hb.z,"v62","v94","v126")  DOT3(Hb.w,"v63","v95","v127")
    s0 += __shfl_xor(s0, 1, 64); s0 += __shfl_xor(s0, 2, 64);
    s1 += __shfl_xor(s1, 1, 64); s1 += __shfl_xor(s1, 2, 64);
    s2 += __shfl_xor(s2, 1, 64); s2 += __shfl_xor(s2, 2, 64);
    float r = sigm(gr + s0);             // bhh_r/z folded into GI bias
    float z = sigm(gz + s1);
    float n = tanh_(gn + r * (s2 + bh_n));
    float hn = (1.f - z) * n + z * hreg;
    hreg = hn;
    if (c == 0) {
      if (wr) Hout[(size_t)t * HDIM + g] = hn;
      ushort* hw = (ushort*)&hb[buf ^ 1][g >> 6][0];
      hw[g & 63] = __builtin_bit_cast(uint16_t, (_Float16)hn);
    }
    __syncthreads();
    buf ^= 1;
  }
}

// ---------------------------------------------------------------- GAT pieces
__global__ __launch_bounds__(256) void esed_k(const float* __restrict__ Hg,
                                              const float* __restrict__ a_s,
                                              const float* __restrict__ a_d,
                                              float* __restrict__ es, float* __restrict__ ed) {
  int idx = blockIdx.x * 256 + threadIdx.x;
  if (idx >= N_NODES * HEADS) return;
  int n = idx >> 3, hd = idx & 7;
  const float* hp = Hg + (size_t)n * HC + hd * DH;
  float s = 0, d = 0;
#pragma unroll
  for (int i = 0; i < DH; i++) {
    float h = hp[i];
    s = fmaf(h, a_s[hd * DH + i], s);
    d = fmaf(h, a_d[hd * DH + i], d);
  }
  es[idx] = s; ed[idx] = d;
}

__global__ __launch_bounds__(256) void esmax_k(const float* __restrict__ es,
                                               unsigned* __restrict__ m) {
  int idx = blockIdx.x * 256 + threadIdx.x;
  float v = (idx < N_NODES * HEADS) ? es[idx] : -1e30f;
#pragma unroll
  for (int mask = 32; mask >= 8; mask >>= 1) v = fmaxf(v, __shfl_xor(v, mask, 64));
  if ((threadIdx.x & 63) < 8) atomicMax(&m[threadIdx.x & 7], fenc(v));
}

// ---------------------------------------------------------------- CSR build
__global__ __launch_bounds__(256) void deg_k(const int* __restrict__ ei, int* __restrict__ deg) {
  int e = blockIdx.x * 256 + threadIdx.x;
  if (e >= E_EDGES) return;
  atomicAdd(&deg[ei[E_EDGES + e]], 1);
}

__global__ __launch_bounds__(1024) void scan_k(const int* __restrict__ deg, int* __restrict__ off) {
  __shared__ int wsum[16];
  __shared__ int carry;
  int tid = threadIdx.x, lane = tid & 63, wv = tid >> 6;
  if (tid == 0) carry = 0;
  __syncthreads();
  for (int base = 0; base < N_NODES; base += 1024) {
    int i = base + tid;
    int v = (i < N_NODES) ? deg[i] : 0;
    int s = v;
#pragma unroll
    for (int d = 1; d < 64; d <<= 1) {
      int t = __shfl_up(s, d, 64);
      if (lane >= d) s += t;
    }
    if (lane == 63) wsum[wv] = s;
    __syncthreads();
    if (wv == 0 && lane < 16) {
      int t = wsum[lane];
#pragma unroll
      for (int d = 1; d < 16; d <<= 1) {
        int u = __shfl_up(t, d, 64);
        if (lane >= d) t += u;
      }
      wsum[lane] = t;
    }
    __syncthreads();
    int prev = (wv > 0) ? wsum[wv - 1] : 0;
    int excl = carry + prev + s - v;
    if (i < N_NODES) off[i] = excl;
    int total = wsum[15];
    __syncthreads();
    if (tid == 0) carry += total;
    __syncthreads();
  }
  if (tid == 0) off[N_NODES] = carry;
}

__global__ __launch_bounds__(256) void scatter_k(const int* __restrict__ ei,
                                                 const int* __restrict__ off,
                                                 int* __restrict__ cnt,
                                                 int* __restrict__ csr_src) {
  int e = blockIdx.x * 256 + threadIdx.x;
  if (e >= E_EDGES) return;
  int d = ei[E_EDGES + e];
  int pos = off[d] + atomicAdd(&cnt[d], 1);
  csr_src[pos] = ei[e];
}

// ---------------------------------------------------------------- GAT gather (1 wave / dst)
template <int RELU>
__global__ __launch_bounds__(256) void gather_k(const int* __restrict__ off,
                                                const int* __restrict__ csr_src,
                                                const float* __restrict__ es,
                                                const float* __restrict__ ed,
                                                const unsigned* __restrict__ esm,
                                                const float* __restrict__ Hg,
                                                const float* __restrict__ bias,
                                                float* __restrict__ out) {
  int wv = threadIdx.x >> 6, lane = threadIdx.x & 63;
  int d = blockIdx.x * 4 + wv;
  if (d >= N_NODES) return;
  int hd0 = lane >> 4, hd1 = 4 + (lane >> 4);
  float ed0 = ed[d * 8 + hd0], ed1 = ed[d * 8 + hd1];
  float cb0 = leaky(fdec(esm[hd0]) + ed0);
  float cb1 = leaky(fdec(esm[hd1]) + ed1);
  int e0 = off[d], e1 = off[d + 1];
  float acc0 = 0, acc1 = 0, den0 = 0, den1 = 0;
  for (int i = e0; i < e1; i++) {
    int s = csr_src[i];
    float p0 = fexp2(1.44269504f * (leaky(es[s * 8 + hd0] + ed0) - cb0));
    float p1 = fexp2(1.44269504f * (leaky(es[s * 8 + hd1] + ed1) - cb1));
    float h0 = Hg[(size_t)s * HC + lane];
    float h1 = Hg[(size_t)s * HC + 64 + lane];
    acc0 = fmaf(p0, h0, acc0); acc1 = fmaf(p1, h1, acc1);
    den0 += p0; den1 += p1;
  }
  float o0 = acc0 * frcp(den0 + 1e-16f);
  float o1 = acc1 * frcp(den1 + 1e-16f);
  if (RELU) {
    o0 = fmaxf(o0 + bias[lane], 0.f);
    o1 = fmaxf(o1 + bias[64 + lane], 0.f);
  }
  out[(size_t)d * HC + lane] = o0;
  out[(size_t)d * HC + 64 + lane] = o1;
}

// ---------------------------------------------------------------- output heads
__global__ __launch_bounds__(64) void heads_k(const float* __restrict__ xgb,
                                              const float* __restrict__ bg2,
                                              const float* __restrict__ H2,
                                              const float* __restrict__ Wc, const float* __restrict__ bc,
                                              const float* __restrict__ Wmu, const float* __restrict__ bmu,
                                              const float* __restrict__ Wm, const float* __restrict__ bm,
                                              float* __restrict__ out) {
  int n = blockIdx.x, l = threadIdx.x;
  __shared__ float xg[HC];
  __shared__ float xr[HDIM];
  for (int i = l; i < HC; i += 64) xg[i] = xgb[(size_t)n * HC + i] + bg2[i];
  for (int i = l; i < HDIM; i += 64) xr[i] = fmaxf(H2[(size_t)n * HDIM + i], 0.f);
  __syncthreads();
  float acc = bm[l];
#pragma unroll 8
  for (int k = 0; k < HC; k++) acc = fmaf(xg[k], Wm[k * MS + l], acc);
  out[N_NODES + (size_t)n * MS + l] = tanh_(acc);
  if (l < NA) {
    float a = bmu[l];
    for (int k = 0; k < HDIM; k++) a = fmaf(xr[k], Wmu[k * NA + l], a);
    for (int k = 0; k < HC; k++) a = fmaf(xg[k], Wmu[(HDIM + k) * NA + l], a);
    out[N_NODES + (size_t)N_NODES * MS + (size_t)n * NA + l] = tanh_(a);
  }
  if (l == 0) {
    float a = bc[0];
    for (int k = 0; k < HC; k++) a = fmaf(xg[k], Wc[k], a);
    out[n] = sigm(a);
  }
}

// ---------------------------------------------------------------- launch
extern "C" void kernel_launch(void* const* d_in, const int* in_sizes, int n_in,
                              void* d_out, int out_size, void* d_ws, size_t ws_size,
                              hipStream_t stream) {
  const float* state = (const float*)d_in[0];
  const float* message = (const float*)d_in[1];
  const int* ei = (const int*)d_in[2];
  const float* Wfc1 = (const float*)d_in[3]; const float* bfc1 = (const float*)d_in[4];
  const float* Wfc2 = (const float*)d_in[5]; const float* bfc2 = (const float*)d_in[6];
  const float* Wih0 = (const float*)d_in[7]; const float* Whh0 = (const float*)d_in[8];
  const float* bih0 = (const float*)d_in[9]; const float* bhh0 = (const float*)d_in[10];
  const float* Wih1 = (const float*)d_in[11]; const float* Whh1 = (const float*)d_in[12];
  const float* bih1 = (const float*)d_in[13]; const float* bhh1 = (const float*)d_in[14];
  const float* Wg1 = (const float*)d_in[15]; const float* as1 = (const float*)d_in[16];
  const float* ad1 = (const float*)d_in[17]; const float* bg1 = (const float*)d_in[18];
  const float* Wg2 = (const float*)d_in[19]; const float* as2 = (const float*)d_in[20];
  const float* ad2 = (const float*)d_in[21]; const float* bg2 = (const float*)d_in[22];
  const float* Wc = (const float*)d_in[23]; const float* bc = (const float*)d_in[24];
  const float* Wmu = (const float*)d_in[25]; const float* bmu = (const float*)d_in[26];
  const float* Wm = (const float*)d_in[27]; const float* bm = (const float*)d_in[28];

  float* ws = (float*)d_ws;
  float* GI = ws;                       // [20000 x 768]; dead after scans, region reused:
  float* HGa = ws;                      //   [20000 x 128] gat h
  float* HGb = ws + 2560000;            //   [20000 x 128] aggregation out (layer2)
  float* X2  = ws + 5120000;            //   [20000 x 128] relu(gat1+bg1)
  float* ES  = ws + 7680000;            //   [20000 x 8]
  float* ED  = ws + 7840000;            //   [20000 x 8]
  unsigned* ESM = (unsigned*)(ws + 8160000);  // [8]
  int* DEG = (int*)(ws + 8200000);      //   [20000]
  int* OFF = (int*)(ws + 8230000);      //   [20001]
  int* CNT = (int*)(ws + 8260000);      //   [20000]
  int* CSR = (int*)(ws + 8300000);      //   [640000]
  float* X  = ws + 15360000;            // [20000 x 256], reused as H1
  float* H2 = ws + 20480000;            // [20000 x 256]
  // B2 in the H2 region head: dead during both GI GEMMs, overwritten by scan 1.
  float* B2  = H2;                      //   [768] combined GI bias
  uint32_t* Wpk = (uint32_t*)(ws + 25600000); // [24*4096 dwords]
  float* out = (float*)d_out;

  int rt = (N_NODES + 63) / 64;  // 313 row tiles

  gemm_k<GF_BIAS | GF_RELU_OUT><<<rt * 4, 256, 0, stream>>>(state, Wfc1, bfc1, X, N_NODES, 64, 256);
  gemm_k<GF_BIAS | GF_RELU_OUT | GF_ACC><<<rt * 4, 256, 0, stream>>>(message, Wfc2, bfc2, X, N_NODES, 64, 256);
  // GRU layer 0
  prep_b<<<3, 256, 0, stream>>>(bih0, bhh0, B2);
  gemm_k<GF_BIAS | GF_BT><<<rt * 12, 256, 0, stream>>>(X, Wih0, B2, GI, N_NODES, 256, G3);
  prep_w<<<384, 256, 0, stream>>>(Whh0, Wpk);
  gru_scan<<<8, 1024, 0, stream>>>(GI, Wpk, bhh0, X);  // H1 overwrites X
  // GRU layer 1
  prep_b<<<3, 256, 0, stream>>>(bih1, bhh1, B2);
  gemm_k<GF_BIAS | GF_BT><<<rt * 12, 256, 0, stream>>>(X, Wih1, B2, GI, N_NODES, 256, G3);
  prep_w<<<384, 256, 0, stream>>>(Whh1, Wpk);
  gru_scan<<<8, 1024, 0, stream>>>(GI, Wpk, bhh1, H2);
  // CSR build
  hipMemsetAsync(DEG, 0, N_NODES * 4, stream);
  hipMemsetAsync(CNT, 0, N_NODES * 4, stream);
  deg_k<<<2500, 256, 0, stream>>>(ei, DEG);
  scan_k<<<1, 1024, 0, stream>>>(DEG, OFF);
  scatter_k<<<2500, 256, 0, stream>>>(ei, OFF, CNT, CSR);
  // GAT layer 1
  gemm_k<GF_RELU_A><<<rt * 2, 256, 0, stream>>>(H2, Wg1, nullptr, HGa, N_NODES, 256, HC);
  esed_k<<<625, 256, 0, stream>>>(HGa, as1, ad1, ES, ED);
  hipMemsetAsync(ESM, 0, 8 * 4, stream);
  esmax_k<<<625, 256, 0, stream>>>(ES, ESM);
  gather_k<1><<<5000, 256, 0, stream>>>(OFF, CSR, ES, ED, ESM, HGa, bg1, X2);
  // GAT layer 2
  gemm_k<0><<<rt * 2, 256, 0, stream>>>(X2, Wg2, nullptr, HGa, N_NODES, HC, HC);
  esed_k<<<625, 256, 0, stream>>>(HGa, as2, ad2, ES, ED);
  hipMemsetAsync(ESM, 0, 8 * 4, stream);
  esmax_k<<<625, 256, 0, stream>>>(ES, ESM);
  gather_k<0><<<5000, 256, 0, stream>>>(OFF, CSR, ES, ED, ESM, HGa, nullptr, HGb);
  // heads
  heads_k<<<N_NODES, 64, 0, stream>>>(HGb, bg2, H2, Wc, bc, Wmu, bmu, Wm, bm, out);
}